// Round 1
// baseline (132.011 us; speedup 1.0000x reference)
//
#include <hip/hip_runtime.h>
#include <hip/hip_bf16.h>
#include <stdint.h>

// Problem constants (fixed by reference: N=4096, D=1024)
#define N_ROWS 4096
#define DIMS   1024
#define BM 128
#define BN 128
#define BK 64
#define TGRID 32              // 4096/128
#define NTILES 528            // 32*33/2 upper-triangular tiles

typedef __attribute__((ext_vector_type(8))) short short8;
typedef __attribute__((ext_vector_type(4))) float f32x4;

// round-to-nearest-even float -> bf16 (bit-exact, no API dependence)
__device__ __forceinline__ unsigned short f2bf(float f) {
  union { float f; unsigned int u; } c; c.f = f;
  unsigned int u = c.u;
  unsigned int r = (u + 0x7fffu + ((u >> 16) & 1u)) >> 16;
  return (unsigned short)r;
}

// async global->LDS, 16B per lane; LDS dest = wave-uniform base + lane*16
__device__ __forceinline__ void async_cp16(const unsigned short* g, void* lds) {
  __builtin_amdgcn_global_load_lds(
      (const __attribute__((address_space(1))) void*)g,
      (__attribute__((address_space(3))) void*)lds, 16, 0, 0);
}

// ---------------------------------------------------------------------------
// Kernel 1: row-normalize fp32 -> unit-norm bf16 rows. One wave per row.
// Also zeroes d_out (runs before the main kernel on the same stream).
// ---------------------------------------------------------------------------
__global__ __launch_bounds__(256) void normalize_bf16_kernel(
    const float* __restrict__ fq, const float* __restrict__ fk,
    unsigned short* __restrict__ qn, unsigned short* __restrict__ kn,
    float* __restrict__ out) {
  if (blockIdx.x == 0 && blockIdx.y == 0 && threadIdx.x == 0) out[0] = 0.0f;
  const int w = threadIdx.x >> 6;
  const int lane = threadIdx.x & 63;
  const int row = blockIdx.x * 4 + w;
  const float* src = blockIdx.y ? fk : fq;
  unsigned short* dst = blockIdx.y ? kn : qn;
  const float4* s4 = (const float4*)(src + (size_t)row * DIMS);
  float4 v[4];
  float ss = 0.0f;
  #pragma unroll
  for (int s = 0; s < 4; ++s) {
    v[s] = s4[lane + 64 * s];
    ss += v[s].x * v[s].x + v[s].y * v[s].y + v[s].z * v[s].z + v[s].w * v[s].w;
  }
  #pragma unroll
  for (int off = 32; off > 0; off >>= 1) ss += __shfl_xor(ss, off);
  // q = x/(||x||+1e-7) then / max(||q||_i ||q||_j, 1e-8) net-cancels to x/||x||
  const float scale = 1.0f / sqrtf(ss);
  ushort4* d4 = (ushort4*)(dst + (size_t)row * DIMS);
  #pragma unroll
  for (int s = 0; s < 4; ++s) {
    ushort4 o;
    o.x = f2bf(v[s].x * scale);
    o.y = f2bf(v[s].y * scale);
    o.z = f2bf(v[s].z * scale);
    o.w = f2bf(v[s].w * scale);
    d4[lane + 64 * s] = o;
  }
}

// ---------------------------------------------------------------------------
// Kernel 2: fused upper-triangular (Sq - Sk)^2 reduction.
// Block = 256 threads (4 waves), tile 128x128, BK=64, per-wave 64x64 x2 mats.
// LDS layout per tile: row-major [128][64] bf16 in 16B chunks, chunk slot
// swizzled by XOR(row&7) — consistent between global_load_lds writer and
// ds_read_b128 fragment reader.
// ---------------------------------------------------------------------------
__global__ __launch_bounds__(256, 2) void constloss_main_kernel(
    const unsigned short* __restrict__ qn,
    const unsigned short* __restrict__ kn,
    float* __restrict__ out) {
  __shared__ __align__(16) char smem[4 * BM * BK * 2];  // 64 KiB: Aq,Bq,Ak,Bk

  // unrank blockIdx.x -> (I,J) with I<=J over a 32x32 tile grid
  int I = 0, rem = blockIdx.x;
  while (rem >= (TGRID - I)) { rem -= (TGRID - I); ++I; }
  const int J = I + rem;

  const int tid = threadIdx.x;
  const int w = tid >> 6;
  const int lane = tid & 63;

  // --- staging setup: wave w owns one tile: 0:Aq(I,q) 1:Bq(J,q) 2:Ak(I,k) 3:Bk(J,k)
  const unsigned short* sbase = (w & 2) ? kn : qn;
  const int rblk = (w & 1) ? J : I;
  const unsigned short* srow = sbase + (size_t)rblk * BM * DIMS;
  const int rl = lane >> 3;            // row within 8-row group
  const int cl = (lane & 7) ^ rl;      // swizzled global 16B-chunk index
  const unsigned short* gsrc0 = srow + (size_t)rl * DIMS + cl * 8;
  char* ldsTile = smem + w * (BM * BK * 2);  // 16 KiB per tile

  // --- compute setup: wave (wr,wc) computes 64x64 of the 128x128 tile
  const int wr = w >> 1, wc = w & 1;
  const int ml = lane & 15;
  const int quad = lane >> 4;
  const int ar0 = wr * 64, bc0 = wc * 64;

  f32x4 accq[4][4] = {};
  f32x4 acck[4][4] = {};

  for (int kk = 0; kk < DIMS; kk += BK) {
    // stage 4 x 16KB tiles: each wave 16 x (64 lanes x 16B) writes
    const unsigned short* g = gsrc0 + kk;
    #pragma unroll
    for (int s = 0; s < 16; ++s)
      async_cp16(g + s * 8 * DIMS, ldsTile + s * 1024);
    __syncthreads();

    #pragma unroll
    for (int ks = 0; ks < BK; ks += 32) {
      // A/B frag: element [r][ks + quad*8 + j]; chunk=(ks>>3)|quad, slot=chunk^(r&7)
      const int slot = (((ks >> 3) | quad) ^ (ml & 7)) * 16;
      short8 aq[4], bq[4], ak[4], bk[4];
      #pragma unroll
      for (int i = 0; i < 4; ++i) {
        const int ra = (ar0 + i * 16 + ml) * (BK * 2);
        const int rb = (bc0 + i * 16 + ml) * (BK * 2);
        aq[i] = *(const short8*)(smem + 0     + ra + slot);
        bq[i] = *(const short8*)(smem + 16384 + rb + slot);
        ak[i] = *(const short8*)(smem + 32768 + ra + slot);
        bk[i] = *(const short8*)(smem + 49152 + rb + slot);
      }
      #pragma unroll
      for (int i = 0; i < 4; ++i) {
        #pragma unroll
        for (int j = 0; j < 4; ++j) {
          accq[i][j] = __builtin_amdgcn_mfma_f32_16x16x32_bf16(aq[i], bq[j], accq[i][j], 0, 0, 0);
          acck[i][j] = __builtin_amdgcn_mfma_f32_16x16x32_bf16(ak[i], bk[j], acck[i][j], 0, 0, 0);
        }
      }
    }
    __syncthreads();
  }

  // --- epilogue: weighted masked (sq-sk)^2, block reduce, one atomic
  // C/D layout: col = lane&15, row = quad*4 + reg
  float local = 0.0f;
  #pragma unroll
  for (int i = 0; i < 4; ++i) {
    #pragma unroll
    for (int j = 0; j < 4; ++j) {
      #pragma unroll
      for (int p = 0; p < 4; ++p) {
        const float d = accq[i][j][p] - acck[i][j][p];
        float t = d * d;
        if (I == J) {
          const int gr = ar0 + i * 16 + quad * 4 + p;
          const int gc = bc0 + j * 16 + ml;
          if (gr == gc) t = 0.0f;   // mask diagonal
        }
        local += t;
      }
    }
  }
  if (I != J) local *= 2.0f;  // off-diagonal tiles count for (i,j) and (j,i)

  #pragma unroll
  for (int off = 32; off > 0; off >>= 1) local += __shfl_xor(local, off);
  __syncthreads();  // LDS reads all done (loop-final barrier), safe to reuse
  if (lane == 0) ((float*)smem)[w] = local;
  __syncthreads();
  if (tid == 0) {
    const float t = ((float*)smem)[0] + ((float*)smem)[1] +
                    ((float*)smem)[2] + ((float*)smem)[3];
    atomicAdd(out, t * (1.0f / 16773120.0f));  // / (N*(N-1))
  }
}

extern "C" void kernel_launch(void* const* d_in, const int* in_sizes, int n_in,
                              void* d_out, int out_size, void* d_ws, size_t ws_size,
                              hipStream_t stream) {
  const float* fq = (const float*)d_in[0];
  const float* fk = (const float*)d_in[1];
  unsigned short* qn = (unsigned short*)d_ws;                    // 8 MiB
  unsigned short* kn = qn + (size_t)N_ROWS * DIMS;               // 8 MiB
  float* out = (float*)d_out;

  dim3 g1(N_ROWS / 4, 2);
  normalize_bf16_kernel<<<g1, 256, 0, stream>>>(fq, fk, qn, kn, out);
  constloss_main_kernel<<<NTILES, 256, 0, stream>>>(qn, kn, out);
}

// Round 3
// 120.739 us; speedup vs baseline: 1.0934x; 1.0934x over previous
//
#include <hip/hip_runtime.h>
#include <stdint.h>

// N=4096 rows, D=1024 -> M = [Q|K] : 4096 x 2048, Mt = M^T : 2048 x 4096 bf16
// loss = [ sum_{a,b} s_a s_b (M^T M)_ab^2 ] / (N*(N-1)),  s_a = +1 (a<1024), -1 else
// KSPLIT partials are SUMMED before squaring (R2 bug: squared partials).
#define N_ROWS 4096
#define DIMS   1024
#define BM 128
#define BK 64
#define TG 16          // 2048/128 tile grid
#define NTRI 136       // 16*17/2 upper-triangular tiles
#define KSPLIT 4
#define KCHUNK 1024    // 4096/KSPLIT

typedef __attribute__((ext_vector_type(8))) short short8;
typedef __attribute__((ext_vector_type(8))) unsigned short ushort8;
typedef __attribute__((ext_vector_type(4))) float f32x4;

__device__ __forceinline__ unsigned short f2bf(float f) {
  union { float f; unsigned int u; } c; c.f = f;
  unsigned int u = c.u;
  return (unsigned short)((u + 0x7fffu + ((u >> 16) & 1u)) >> 16);
}
__device__ __forceinline__ float bf2f(unsigned short v) {
  union { float f; unsigned int u; } c; c.u = ((unsigned int)v) << 16;
  return c.f;
}

// async global->LDS, 16B/lane; LDS dest = wave-uniform base + lane*16
__device__ __forceinline__ void async_cp16(const unsigned short* g, void* lds) {
  __builtin_amdgcn_global_load_lds(
      (const __attribute__((address_space(1))) void*)g,
      (__attribute__((address_space(3))) void*)lds, 16, 0, 0);
}

// ---------------------------------------------------------------------------
// K1: inverse row norms of feat_q / feat_k (one wave per row); zero d_out.
// ---------------------------------------------------------------------------
__global__ __launch_bounds__(256) void rownorm_kernel(
    const float* __restrict__ fq, const float* __restrict__ fk,
    float* __restrict__ invq, float* __restrict__ invk, float* __restrict__ out) {
  if (blockIdx.x == 0 && blockIdx.y == 0 && threadIdx.x == 0) out[0] = 0.0f;
  const int w = threadIdx.x >> 6, lane = threadIdx.x & 63;
  const int row = blockIdx.x * 4 + w;
  const float* src = blockIdx.y ? fk : fq;
  float* dst = blockIdx.y ? invk : invq;
  const float4* s4 = (const float4*)(src + (size_t)row * DIMS);
  float ss = 0.0f;
  #pragma unroll
  for (int s = 0; s < 4; ++s) {
    float4 v = s4[lane + 64 * s];
    ss += v.x * v.x + v.y * v.y + v.z * v.z + v.w * v.w;
  }
  #pragma unroll
  for (int off = 32; off > 0; off >>= 1) ss += __shfl_xor(ss, off);
  if (lane == 0) dst[row] = 1.0f / sqrtf(ss);  // eps terms cancel to ~3e-9 rel
}

// ---------------------------------------------------------------------------
// K2: build Mt[a][i] = normalized bf16, transposed via LDS (R2-unchanged).
// ---------------------------------------------------------------------------
__global__ __launch_bounds__(256) void transpose_scale_kernel(
    const float* __restrict__ fq, const float* __restrict__ fk,
    const float* __restrict__ invq, const float* __restrict__ invk,
    unsigned short* __restrict__ Mt) {
  __shared__ unsigned short tile[64][260];
  const int i0 = blockIdx.x * 256;
  const int a0 = blockIdx.y * 64;
  const int w = threadIdx.x >> 6, lane = threadIdx.x & 63;
  const float* src;
  const float* inv;
  int acol;
  if (a0 < DIMS) { src = fq; inv = invq; acol = a0 + lane; }
  else           { src = fk; inv = invk; acol = a0 - DIMS + lane; }

  for (int c0 = 0; c0 < 64; c0 += 4) {
    ushort4 v;
    unsigned short* vp = (unsigned short*)&v;
    #pragma unroll
    for (int c = 0; c < 4; ++c) {
      const int i = i0 + w * 64 + c0 + c;
      vp[c] = f2bf(src[(size_t)i * DIMS + acol] * inv[i]);
    }
    *(ushort4*)&tile[lane][w * 64 + c0] = v;
  }
  __syncthreads();
  #pragma unroll
  for (int r = 0; r < 16; ++r) {
    const int al = w * 16 + r;
    ushort4 v = *(const ushort4*)&tile[al][lane * 4];
    *(ushort4*)(Mt + (size_t)(a0 + al) * N_ROWS + i0 + lane * 4) = v;
  }
}

// ---------------------------------------------------------------------------
// K3: partial Gram tiles. Block = (tri-tile t, k-chunk kc); computes 128x128
// partial over K=1024 and stores it (bf16) to its own slab. NO squaring here.
// ---------------------------------------------------------------------------
__global__ __launch_bounds__(256, 4) void gram_partial_kernel(
    const unsigned short* __restrict__ Mt, unsigned short* __restrict__ Gp) {
  __shared__ __align__(16) char smem[2 * BM * BK * 2];  // 32 KiB

  const int t = blockIdx.x >> 2;
  const int kc = blockIdx.x & 3;
  int I = 0, rem = t;
  while (rem >= (TG - I)) { rem -= (TG - I); ++I; }
  const int J = I + rem;

  const int tid = threadIdx.x, w = tid >> 6, lane = tid & 63;

  // staging: waves 0,1 -> A (rows of block I); waves 2,3 -> B (rows of J)
  const int isB = w >> 1;
  const int rblk = isB ? J : I;
  const int rl = lane >> 3;
  const int cl = (lane & 7) ^ rl;          // chunk swizzle (verified R1)
  const bool skipStage = (isB && I == J);  // diag tile: B aliases A
  const unsigned short* gsrc0 =
      Mt + (size_t)(rblk * BM + (w & 1) * 64 + rl) * N_ROWS + kc * KCHUNK + cl * 8;
  char* ldsBase = smem + isB * 16384 + (w & 1) * 8192;
  const int bOff = (I == J) ? 0 : 16384;

  const int wr = w >> 1, wc = w & 1;
  const int ml = lane & 15, quad = lane >> 4;
  const int ar0 = wr * 64, bc0 = wc * 64;

  f32x4 acc[4][4] = {};

  for (int kk = 0; kk < KCHUNK; kk += BK) {
    if (!skipStage) {
      const unsigned short* g = gsrc0 + kk;
      #pragma unroll
      for (int s = 0; s < 8; ++s)
        async_cp16(g + (size_t)s * 8 * N_ROWS, ldsBase + s * 1024);
    }
    __syncthreads();
    #pragma unroll
    for (int ks = 0; ks < BK; ks += 32) {
      const int slot = (((ks >> 3) | quad) ^ (ml & 7)) * 16;
      short8 a[4], b[4];
      #pragma unroll
      for (int i = 0; i < 4; ++i) {
        const int ra = (ar0 + i * 16 + ml) * (BK * 2);
        const int rb = (bc0 + i * 16 + ml) * (BK * 2);
        a[i] = *(const short8*)(smem + ra + slot);
        b[i] = *(const short8*)(smem + bOff + rb + slot);
      }
      #pragma unroll
      for (int i = 0; i < 4; ++i)
        #pragma unroll
        for (int j = 0; j < 4; ++j)
          acc[i][j] = __builtin_amdgcn_mfma_f32_16x16x32_bf16(a[i], b[j], acc[i][j], 0, 0, 0);
    }
    __syncthreads();
  }

  // epilogue: store raw bf16 partial tile. C/D: col=lane&15, row=quad*4+reg
  unsigned short* slab = Gp + (size_t)blockIdx.x * (BM * BM);
  #pragma unroll
  for (int i = 0; i < 4; ++i)
    #pragma unroll
    for (int j = 0; j < 4; ++j)
      #pragma unroll
      for (int p = 0; p < 4; ++p) {
        const int r = ar0 + i * 16 + quad * 4 + p;
        const int c = bc0 + j * 16 + ml;
        slab[r * BM + c] = f2bf(acc[i][j][p]);
      }
}

// ---------------------------------------------------------------------------
// K4: sum KSPLIT partials (fp32), square, sign/weight, reduce -> atomicAdd.
// Grid: NTRI*8 blocks; block handles 2048 entries of one tile (8/thread).
// ---------------------------------------------------------------------------
__global__ __launch_bounds__(256) void square_reduce_kernel(
    const unsigned short* __restrict__ Gp, float* __restrict__ out) {
  __shared__ float wsum[4];
  const int t = blockIdx.x >> 3;
  const int seg = blockIdx.x & 7;
  int I = 0, rem = t;
  while (rem >= (TG - I)) { rem -= (TG - I); ++I; }
  const int J = I + rem;

  const unsigned short* base =
      Gp + (size_t)t * (KSPLIT * BM * BM) + seg * 2048 + threadIdx.x * 8;
  float s[8] = {0, 0, 0, 0, 0, 0, 0, 0};
  #pragma unroll
  for (int kc = 0; kc < KSPLIT; ++kc) {
    const ushort8 v = *(const ushort8*)(base + kc * (BM * BM));
    #pragma unroll
    for (int x = 0; x < 8; ++x) s[x] += bf2f(v[x]);
  }
  float local = 0.0f;
  #pragma unroll
  for (int x = 0; x < 8; ++x) local += s[x] * s[x];

  const float sgn = ((I < 8) == (J < 8)) ? 1.0f : -1.0f;
  local *= (I == J ? 1.0f : 2.0f) * sgn;

  #pragma unroll
  for (int off = 32; off > 0; off >>= 1) local += __shfl_xor(local, off);
  const int w = threadIdx.x >> 6, lane = threadIdx.x & 63;
  if (lane == 0) wsum[w] = local;
  __syncthreads();
  if (threadIdx.x == 0) {
    const float ts = wsum[0] + wsum[1] + wsum[2] + wsum[3];
    atomicAdd(out, ts * (1.0f / 16773120.0f));  // / (N*(N-1))
  }
}

extern "C" void kernel_launch(void* const* d_in, const int* in_sizes, int n_in,
                              void* d_out, int out_size, void* d_ws, size_t ws_size,
                              hipStream_t stream) {
  const float* fq = (const float*)d_in[0];
  const float* fk = (const float*)d_in[1];
  float* invq = (float*)d_ws;                                    // 16 KiB
  float* invk = invq + N_ROWS;                                   // 16 KiB
  unsigned short* Mt = (unsigned short*)((char*)d_ws + 32768);   // 16 MiB
  unsigned short* Gp = Mt + (size_t)2048 * N_ROWS;               // 17.8 MiB
  float* out = (float*)d_out;

  rownorm_kernel<<<dim3(N_ROWS / 4, 2), 256, 0, stream>>>(fq, fk, invq, invk, out);
  transpose_scale_kernel<<<dim3(16, 32), 256, 0, stream>>>(fq, fk, invq, invk, Mt);
  gram_partial_kernel<<<NTRI * KSPLIT, 256, 0, stream>>>(Mt, Gp);
  square_reduce_kernel<<<NTRI * 8, 256, 0, stream>>>(Gp, out);
}